// Round 3
// baseline (502.196 us; speedup 1.0000x reference)
//
#include <hip/hip_runtime.h>

#define NCAM 6
#define CCH  128
#define IH   64
#define IW   176
#define NQ   640000           // 200*200*16
#define PIX  (IH * IW)        // 11264 = 352*32
#define LSTR 132              // LDS stride (floats): 16B-aligned, phase-C reads 2-way (free)

// ---------------------------------------------------------------------------
// Kernel 1: transpose img_feats (cam, c, y, x) -> (cam, y, x, c).
// ---------------------------------------------------------------------------
__global__ __launch_bounds__(256) void transpose_kernel(
    const float* __restrict__ in, float* __restrict__ out) {
    __shared__ float tile[32][33];
    const int cam   = blockIdx.z;
    const int pbase = blockIdx.x * 32;
    const int cbase = blockIdx.y * 32;
    const int tx = threadIdx.x, ty = threadIdx.y;

    const float* src = in  + (size_t)cam * CCH * PIX;
    float*       dst = out + (size_t)cam * PIX * CCH;

    #pragma unroll
    for (int j = 0; j < 4; ++j) {
        int c = cbase + ty + j * 8;
        tile[ty + j * 8][tx] = src[(size_t)c * PIX + (pbase + tx)];
    }
    __syncthreads();
    #pragma unroll
    for (int j = 0; j < 4; ++j) {
        int p = pbase + ty + j * 8;
        dst[(size_t)p * CCH + (cbase + tx)] = tile[tx][ty + j * 8];
    }
}

// ---------------------------------------------------------------------------
// Kernel 2: wave-autonomous gather. Each wave owns 16 queries + a private
// LDS slab -> ZERO barriers (in-wave LDS ordering is HW-guaranteed; compiler
// emits fine-grained lgkmcnt/vmcnt). Grid-stride loop keeps waves pipelined:
// a wave's phase-C stores issue and it immediately proceeds to the next
// tile's loads — no cross-wave stall on slow random-latency LLC reads.
//  A) lanes 0..15: resolve highest valid cam, RNE round, base offset -> LDS
//  B) 8 iters: each 32-lane half loads one query's 512B as one coalesced
//     global_load_dwordx4, scales, ds_write_b128 to LDS slab
//  C) 8 iters: LDS->regs (2-way, free) -> float4 stores to out(c,q),
//     4 consecutive float4 = 64B contiguous per c-row
// LDS: 4 waves * 16*132*4 = 33.8 KB -> 4 blocks/CU, 16 waves/CU.
// ---------------------------------------------------------------------------
__global__ __launch_bounds__(256) void gather_wave_kernel(
    const float* __restrict__ imgT,     // (cam, y, x, c)
    const float* __restrict__ points,   // (cam, NQ, 2)
    const int*   __restrict__ valid,    // (cam, NQ) int32
    float*       __restrict__ out,      // (c, NQ)
    int n_tiles) {
    __shared__ float feat[4][16 * LSTR];
    __shared__ int   sbase_s[4][16];
    __shared__ float sscale_s[4][16];

    const int t    = threadIdx.x;
    const int wv   = t >> 6;       // wave 0..3
    const int l    = t & 63;
    const int half = l >> 5;       // 0/1
    const int hl   = l & 31;
    const int qq   = l & 3;        // phase-C: q-quad 0..3
    const int csub = l >> 2;       // phase-C: 0..15

    for (int tile = blockIdx.x; tile < n_tiles; tile += gridDim.x) {
        const int qbase = tile * 64 + wv * 16;

        // ---- Phase A: resolve (lanes 0..15, one query each) ----
        if (l < 16) {
            const int q = qbase + l;
            int sel = -1;
            #pragma unroll
            for (int cam = 0; cam < NCAM; ++cam)
                if (valid[(size_t)cam * NQ + q] != 0) sel = cam;   // highest valid
            const int cam = (sel >= 0) ? sel : 0;
            sscale_s[wv][l] = (sel >= 0) ? 1.0f : 0.0f;
            const float2 pt = ((const float2*)points)[(size_t)cam * NQ + q];
            const int x = __float2int_rn(pt.x);   // RNE == jnp.round
            const int y = __float2int_rn(pt.y);
            sbase_s[wv][l] = ((cam * IH + y) * IW + x) * CCH;      // word offset
        }
        // no barrier: same-wave LDS write->read, HW in-order + lgkmcnt

        // ---- Phase B: coalesced 512B loads -> scaled -> LDS ----
        #pragma unroll
        for (int i = 0; i < 8; ++i) {
            const int   ql = i * 2 + half;
            const float s  = sscale_s[wv][ql];
            const float4 v = *((const float4*)(imgT + sbase_s[wv][ql]) + hl);
            float4* w = (float4*)&feat[wv][ql * LSTR + 4 * hl];
            *w = make_float4(v.x * s, v.y * s, v.z * s, v.w * s);
        }

        // ---- Phase C: LDS -> out (c, q), 64B contiguous per c-row ----
        #pragma unroll
        for (int it = 0; it < 8; ++it) {
            const int c = it * 16 + csub;
            float4 v;
            v.x = feat[wv][(4 * qq + 0) * LSTR + c];
            v.y = feat[wv][(4 * qq + 1) * LSTR + c];
            v.z = feat[wv][(4 * qq + 2) * LSTR + c];
            v.w = feat[wv][(4 * qq + 3) * LSTR + c];
            *(float4*)(out + (size_t)c * NQ + qbase + 4 * qq) = v;
        }
    }
}

// ---------------------------------------------------------------------------
// Fallback: direct gather from (cam, c, y, x) if workspace too small.
// ---------------------------------------------------------------------------
__global__ __launch_bounds__(256) void gather_direct_kernel(
    const float* __restrict__ img,
    const float* __restrict__ points,
    const int*   __restrict__ valid,
    float*       __restrict__ out) {
    const int q = blockIdx.x * 256 + threadIdx.x;

    int sel = -1;
    #pragma unroll
    for (int cam = 0; cam < NCAM; ++cam)
        if (valid[(size_t)cam * NQ + q] != 0) sel = cam;

    const float scale = (sel >= 0) ? 1.0f : 0.0f;
    const int cam = (sel >= 0) ? sel : 0;

    const float2 pt = ((const float2*)points)[(size_t)cam * NQ + q];
    const int x = __float2int_rn(pt.x);
    const int y = __float2int_rn(pt.y);

    const float* src = img + ((size_t)cam * CCH * IH + y) * IW + x;
    #pragma unroll 8
    for (int c = 0; c < CCH; ++c)
        out[(size_t)c * NQ + q] = src[(size_t)c * PIX] * scale;
}

extern "C" void kernel_launch(void* const* d_in, const int* in_sizes, int n_in,
                              void* d_out, int out_size, void* d_ws, size_t ws_size,
                              hipStream_t stream) {
    const float* img    = (const float*)d_in[0];
    const float* points = (const float*)d_in[1];
    const int*   valid  = (const int*)  d_in[2];
    float*       out    = (float*)d_out;

    const size_t need = (size_t)NCAM * CCH * IH * IW * sizeof(float);
    if (ws_size >= need) {
        float* imgT = (float*)d_ws;
        dim3 tb(32, 8, 1);
        dim3 tg(PIX / 32, CCH / 32, NCAM);
        transpose_kernel<<<tg, tb, 0, stream>>>(img, imgT);
        // 2048 persistent-ish blocks (4 resident/CU by LDS): grid-stride over
        // 10000 tiles of 64 queries; balances tails better than exact-resident.
        gather_wave_kernel<<<2048, 256, 0, stream>>>(imgT, points, valid, out,
                                                     NQ / 64);
    } else {
        gather_direct_kernel<<<NQ / 256, 256, 0, stream>>>(img, points, valid, out);
    }
}